// Round 8
// baseline (203.623 us; speedup 1.0000x reference)
//
#include <hip/hip_runtime.h>

#define ROW_F 85        // floats per row
#define NCLS 80         // classes
#define CONF_THRESH 0.25f
#define THREADS 256

// Decisive structural A/B vs the LDS-staging family (R2/R3/R7 all ~192 us
// total): NO LDS, NO DMA, NO barriers, maximum TLP. One thread per row,
// 256-thread blocks, zero LDS -> occupancy limited only by VGPRs (~16-24
// waves/CU vs 7 for every LDS variant). Per-lane reads are sequential dwords
// (row = 340 B, only 4 B aligned -> scalar loads), so each wave-instruction
// touches ~4 NEW 64 B lines (64 lanes x 4 B / 64 B) and re-hits the previous
// instruction's lines in L1 — natural ~6% miss rate with distance-1 reuse;
// residual thrash is absorbed by L2/L3 (HBM FETCH unaffected).
//
// The 80-class argmax chain is 85 independent loads feeding a cmp/cndmask
// chain; the compiler clauses the loads in register-budget-sized batches, and
// 16+ resident waves/CU provide the outstanding-request depth that the
// LDS-phase machines provided via in-flight tiles.
//
// If this lands at the same ~192 us total as R2/R3/R7, four structurally
// independent kernels plateau at the same ~2.5 TB/s effective read rate ->
// external memory-path cap (dirty-L3 read sourcing), i.e. roofline.
__global__ __launch_bounds__(THREADS) void yolo_post_kernel(
    const float* __restrict__ in, float* __restrict__ out, int nrows) {
  const int r = blockIdx.x * THREADS + threadIdx.x;
  if (r >= nrows) return;

  const float* __restrict__ row = in + (long long)r * ROW_F;

  float cx = row[0];
  float cy = row[1];
  float hw = row[2] * 0.5f;
  float hh = row[3] * 0.5f;
  float conf = row[4];

  float best = row[5];
  int bidx = 0;
#pragma unroll
  for (int c = 1; c < NCLS; ++c) {
    float x = row[5 + c];
    bool g = x > best;               // strict > keeps FIRST max (jnp.argmax)
    best = g ? x : best;
    bidx = g ? c : bidx;
  }

  float score = conf * best;
  bool keep = score > CONF_THRESH;

  float2 o01 = keep ? make_float2(cx - hw, cy - hh) : make_float2(0.f, 0.f);
  float2 o23 = keep ? make_float2(cx + hw, cy + hh) : make_float2(0.f, 0.f);
  float2 o45 = keep ? make_float2(score, (float)bidx) : make_float2(0.f, 0.f);

  float2* op = (float2*)(out + (long long)r * 6);   // r*24 B, 8 B aligned
  op[0] = o01;
  op[1] = o23;
  op[2] = o45;
}

extern "C" void kernel_launch(void* const* d_in, const int* in_sizes, int n_in,
                              void* d_out, int out_size, void* d_ws, size_t ws_size,
                              hipStream_t stream) {
  const float* in = (const float*)d_in[0];
  float* out = (float*)d_out;
  const int nrows = in_sizes[0] / ROW_F;                    // 403200
  const int grid = (nrows + THREADS - 1) / THREADS;         // 1575
  yolo_post_kernel<<<grid, THREADS, 0, stream>>>(in, out, nrows);
}